// Round 6
// baseline (284.793 us; speedup 1.0000x reference)
//
#include <hip/hip_runtime.h>
#include <math.h>

#define F_EPS 1e-15f
#define F_BALL 0.99999f              /* 1 - BALL_EPS */
#define F_TANH_ARG_MAX 15.0f
#define F_ATANH_MAX (1.0f - 1e-7f)
#define F_LOG2E 1.4426950408889634f
#define F_LN2   0.6931471805599453f

// ---- fast hardware math ----
__device__ __forceinline__ float rcp_fast(float x) {
    float r = __builtin_amdgcn_rcpf(x);
    return r * (2.0f - x * r);                  // 1 Newton step -> ~fp32 accurate
}
__device__ __forceinline__ float sqrt_fast(float x) { return __builtin_amdgcn_sqrtf(x); }
__device__ __forceinline__ float exp2_fast(float x) { return __builtin_amdgcn_exp2f(x); }
__device__ __forceinline__ float log2_fast(float x) { return __builtin_amdgcn_logf(x); }
__device__ __forceinline__ float exp_fast(float x)  { return exp2_fast(x * F_LOG2E); }

__device__ __forceinline__ float tanh_fast(float x) {
    float ax = fabsf(x);
    float t  = exp2_fast(ax * (-2.0f * F_LOG2E));     // e^{-2|x|}
    float r  = (1.0f - t) * rcp_fast(1.0f + t);
    return copysignf(r, x);
}
__device__ __forceinline__ float atanh_fast(float z) {   // z in [0, 1)
    return (0.5f * F_LN2) * log2_fast((1.0f + z) * rcp_fast(1.0f - z));
}
__device__ __forceinline__ float softplus_fast(float x) {
    return F_LN2 * log2_fast(1.0f + exp2_fast(x * F_LOG2E));
}

// ---- scalar chain, norm-carrying (verified math: absmax 1.95e-3) ----
struct GramS { float X2, Y2, XY; };
struct ChainP { float c, sc, rcp_sc, maxn_pre, maxn_post, s, gamma; };

__device__ __forceinline__ float gnorm2(const GramS& g, float a, float b) {
    return fmaxf(a * a * g.X2 + 2.0f * a * b * g.XY + b * b * g.Y2, 0.0f);
}
__device__ __forceinline__ float gdot(const GramS& g, float au, float bu, float av, float bv) {
    return au * av * g.X2 + (au * bv + bu * av) * g.XY + bu * bv * g.Y2;
}

__device__ __forceinline__ void madd_c(float c, float u2, float v2, float uv,
                                       float au, float bu, float av, float bv,
                                       float& ao, float& bo) {
    float twocuv = 2.0f * c * uv;
    float A = 1.0f + twocuv + c * v2;
    float B = 1.0f - c * u2;
    float rden = rcp_fast(fmaxf(1.0f + twocuv + c * c * u2 * v2, F_EPS));
    ao = (A * au + B * av) * rden;
    bo = (A * bu + B * bv) * rden;
}

__device__ __forceinline__ float pclip(const GramS& g, float maxn_post, float& a, float& b) {
    float n = fmaxf(sqrt_fast(gnorm2(g, a, b)), F_EPS);
    float s = fminf(1.0f, maxn_post * rcp_fast(n));
    a *= s; b *= s;
    return s * n;                       // == min(n, maxn_post)
}

__device__ __forceinline__ float msm_coef(float sc, float rcp_sc, float r,
                                          float n_in, float& n_out) {
    float ne = fmaxf(n_in, F_EPS);
    float z  = fminf(sc * ne, F_ATANH_MAX);
    float w  = tanh_fast(r * atanh_fast(z));
    float m  = w * rcp_fast(sc * ne);
    float aw = fabsf(w);
    float s  = fminf(1.0f, F_BALL * rcp_fast(fmaxf(aw, F_EPS)));   // post_clip
    n_out = s * aw * rcp_sc;
    return m * s;
}

__device__ __forceinline__ float hr_c(float nx, float sc, float rcp_sc,
                                      float maxn_pre, float& n_out) {
    float s1 = fminf(1.0f, maxn_pre * rcp_fast(nx));    // pre_clip (nx >= EPS)
    float n1 = fmaxf(s1 * nx, F_EPS);
    float t  = tanh_fast(sc * n1);                      // >= 0
    float f1 = t * rcp_fast(sc * n1);                   // expmap0 coef
    float s2 = fminf(1.0f, F_BALL * rcp_fast(fmaxf(t, F_EPS)));  // post_clip
    n_out = s2 * t * rcp_sc;
    return s1 * f1 * s2;
}

__device__ __forceinline__ void chain_row(float gX2, float gY2, float gXY,
                                          const ChainP& P, float& fa, float& fb) {
    GramS g; g.X2 = gX2; g.Y2 = gY2; g.XY = gXY;
    const float c = P.c, sc = P.sc, rcp_sc = P.rcp_sc;
    const float maxn_pre = P.maxn_pre, maxn_post = P.maxn_post;

    const float nx = fmaxf(sqrt_fast(gX2), F_EPS);
    const float ny = fmaxf(sqrt_fast(gY2), F_EPS);

    float n_hx, n_hy;
    const float hx = hr_c(nx, sc, rcp_sc, maxn_pre, n_hx);       // hr_x = hx * x
    const float hy = hr_c(ny, sc, rcp_sc, maxn_pre, n_hy);       // hr_y = hy * y

    float n_sx, n_sy;
    const float sxa = hx * msm_coef(sc, rcp_sc, P.s,        n_hx, n_sx);
    const float syb = hy * msm_coef(sc, rcp_sc, 1.0f - P.s, n_hy, n_sy);

    float pa, pb;
    {
        float u2 = n_sx * n_sx, v2 = n_sy * n_sy;
        float uv = sxa * syb * gXY;
        madd_c(c, u2, v2, uv, sxa, 0.0f, 0.0f, syb, pa, pb);
    }
    const float n_p = pclip(g, maxn_post, pa, pb);
    const float np2 = n_p * n_p;

    float xpa, xpb;
    {
        float v2 = n_hx * n_hx;
        float uv = -hx * (pa * gX2 + pb * gXY);
        madd_c(c, np2, v2, uv, -pa, -pb, hx, 0.0f, xpa, xpb);
    }
    const float n_xp = pclip(g, maxn_post, xpa, xpb);

    float ypa, ypb;
    {
        float v2 = n_hy * n_hy;
        float uv = -hy * (pa * gXY + pb * gY2);
        madd_c(c, np2, v2, uv, -pa, -pb, 0.0f, hy, ypa, ypb);
    }
    float n_yp = pclip(g, maxn_post, ypa, ypb);

    float n_ys;
    {
        float m = msm_coef(sc, rcp_sc, P.gamma, n_yp, n_ys);
        ypa *= m; ypb *= m;
    }

    float ha, hb;
    {
        float u2 = n_xp * n_xp, v2 = n_ys * n_ys;
        float uv = gdot(g, xpa, xpb, ypa, ypb);
        madd_c(c, u2, v2, uv, xpa, xpb, ypa, ypb, ha, hb);
    }
    const float n_h = pclip(g, maxn_post, ha, hb);

    float ra, rb;
    {
        float u2 = np2, v2 = n_h * n_h;
        float uv = gdot(g, pa, pb, ha, hb);
        madd_c(c, u2, v2, uv, pa, pb, ha, hb, ra, rb);
    }
    const float n_r = pclip(g, maxn_post, ra, rb);

    const float nrr = fmaxf(n_r, F_EPS);
    const float z   = fminf(sc * nrr, F_ATANH_MAX);
    const float f   = atanh_fast(z) * rcp_fast(sc * nrr);
    fa = f * ra;
    fb = f * rb;
}

// Streaming fused kernel: 1 row per wave-iteration, gram loads consumed
// immediately (no persistent data buffer), chain redundant on all 64 lanes,
// blend RE-READS the row from L2 (guaranteed hit, laundered pointers stop
// CSE). Low VGPR (launch_bounds min-waves=6) -> 24 waves/CU AND compiler
// slack to keep next-iteration loads in flight: blend-shape, fused.
__global__ __launch_bounds__(256, 6) void hra_fused(
    const float* __restrict__ x, const float* __restrict__ y,
    const float* __restrict__ p_curv, const float* __restrict__ p_graw,
    const float* __restrict__ p_gscale, const float* __restrict__ p_scent,
    float* __restrict__ out, int rows)
{
    const int lane = threadIdx.x & 63;
    const int w    = (blockIdx.x << 2) | (threadIdx.x >> 6);
    const int nw   = gridDim.x << 2;

    // wave-uniform params, derived once
    ChainP P;
    P.c         = softplus_fast(p_curv[0]);
    P.sc        = sqrt_fast(P.c);
    P.rcp_sc    = rcp_fast(P.sc);
    P.maxn_pre  = F_TANH_ARG_MAX * P.rcp_sc;
    P.maxn_post = F_BALL * P.rcp_sc;
    P.s         = rcp_fast(1.0f + exp_fast(-p_scent[0]));      // sigmoid
    P.gamma     = (1.0f + softplus_fast(p_gscale[0])) * tanh_fast(p_graw[0]);

    for (int row = w; row < rows; row += nw) {
        const float4* xr = (const float4*)(x + (size_t)row * 768) + lane;
        const float4* yr = (const float4*)(y + (size_t)row * 768) + lane;

        // ---- gram phase: loads consumed straight into partial sums ----
        float4 x0 = xr[0],   y0 = yr[0];
        float4 x1 = xr[64],  y1 = yr[64];
        float4 x2 = xr[128], y2 = yr[128];

        float sxx = x0.x*x0.x + x0.y*x0.y + x0.z*x0.z + x0.w*x0.w
                  + x1.x*x1.x + x1.y*x1.y + x1.z*x1.z + x1.w*x1.w
                  + x2.x*x2.x + x2.y*x2.y + x2.z*x2.z + x2.w*x2.w;
        float syy = y0.x*y0.x + y0.y*y0.y + y0.z*y0.z + y0.w*y0.w
                  + y1.x*y1.x + y1.y*y1.y + y1.z*y1.z + y1.w*y1.w
                  + y2.x*y2.x + y2.y*y2.y + y2.z*y2.z + y2.w*y2.w;
        float sxy = x0.x*y0.x + x0.y*y0.y + x0.z*y0.z + x0.w*y0.w
                  + x1.x*y1.x + x1.y*y1.y + x1.z*y1.z + x1.w*y1.w
                  + x2.x*y2.x + x2.y*y2.y + x2.z*y2.z + x2.w*y2.w;

        // ---- wave reduce (3 sums x 6 butterfly stages) ----
#pragma unroll
        for (int o = 32; o > 0; o >>= 1) {
            sxx += __shfl_xor(sxx, o, 64);
            syy += __shfl_xor(syy, o, 64);
            sxy += __shfl_xor(sxy, o, 64);
        }

        // ---- scalar chain, redundant on all 64 lanes (no shuffles needed) ----
        float fa, fb;
        chain_row(sxx, syy, sxy, P, fa, fb);

        // ---- blend phase: re-read row from L2 (laundered ptrs block CSE) ----
        const float4* xr2 = xr;
        const float4* yr2 = yr;
        asm volatile("" : "+v"(xr2));
        asm volatile("" : "+v"(yr2));
        float4* outr = (float4*)(out + (size_t)row * 768) + lane;
#pragma unroll
        for (int j = 0; j < 3; ++j) {
            const float4 a = xr2[64 * j];
            const float4 b = yr2[64 * j];
            float4 o;
            o.x = fa * a.x + fb * b.x;
            o.y = fa * a.y + fb * b.y;
            o.z = fa * a.z + fb * b.z;
            o.w = fa * a.w + fb * b.w;
            outr[64 * j] = o;
        }
    }
}

extern "C" void kernel_launch(void* const* d_in, const int* in_sizes, int n_in,
                              void* d_out, int out_size, void* d_ws, size_t ws_size,
                              hipStream_t stream) {
    const float* x = (const float*)d_in[0];
    const float* y = (const float*)d_in[1];
    const float* curv = (const float*)d_in[2];
    const float* graw = (const float*)d_in[3];
    const float* gscale = (const float*)d_in[4];
    const float* scent = (const float*)d_in[5];
    float* out = (float*)d_out;

    const int rows = in_sizes[0] / 768;          // 64*577 = 36928
    // persistent grid: 2048 blocks = 8 blocks/CU attempted, VGPR-capped at 6;
    // each wave handles ~4.5 rows via grid-stride
    int blocks = (rows + 3) / 4;
    if (blocks > 2048) blocks = 2048;

    hipLaunchKernelGGL(hra_fused, dim3(blocks), dim3(256), 0, stream,
                       x, y, curv, graw, gscale, scent, out, rows);
}

// Round 8
// 279.719 us; speedup vs baseline: 1.0181x; 1.0181x over previous
//
#include <hip/hip_runtime.h>
#include <math.h>

#define F_EPS 1e-15f
#define F_BALL 0.99999f              /* 1 - BALL_EPS */
#define F_TANH_ARG_MAX 15.0f
#define F_ATANH_MAX (1.0f - 1e-7f)
#define F_LOG2E 1.4426950408889634f
#define F_LN2   0.6931471805599453f

// ---- fast hardware math ----
__device__ __forceinline__ float rcp_fast(float x) {
    float r = __builtin_amdgcn_rcpf(x);
    return r * (2.0f - x * r);                  // 1 Newton step -> ~fp32 accurate
}
__device__ __forceinline__ float sqrt_fast(float x) { return __builtin_amdgcn_sqrtf(x); }
__device__ __forceinline__ float exp2_fast(float x) { return __builtin_amdgcn_exp2f(x); }
__device__ __forceinline__ float log2_fast(float x) { return __builtin_amdgcn_logf(x); }
__device__ __forceinline__ float exp_fast(float x)  { return exp2_fast(x * F_LOG2E); }

__device__ __forceinline__ float tanh_fast(float x) {
    float ax = fabsf(x);
    float t  = exp2_fast(ax * (-2.0f * F_LOG2E));     // e^{-2|x|}
    float r  = (1.0f - t) * rcp_fast(1.0f + t);
    return copysignf(r, x);
}
__device__ __forceinline__ float atanh_fast(float z) {   // z in [0, 1)
    return (0.5f * F_LN2) * log2_fast((1.0f + z) * rcp_fast(1.0f - z));
}
__device__ __forceinline__ float softplus_fast(float x) {
    return F_LN2 * log2_fast(1.0f + exp2_fast(x * F_LOG2E));
}

// ---- scalar chain, norm-carrying (verified math: absmax 1.95e-3) ----
struct GramS { float X2, Y2, XY; };
struct ChainP { float c, sc, rcp_sc, maxn_pre, maxn_post, s, gamma; };

__device__ __forceinline__ float gnorm2(const GramS& g, float a, float b) {
    return fmaxf(a * a * g.X2 + 2.0f * a * b * g.XY + b * b * g.Y2, 0.0f);
}
__device__ __forceinline__ float gdot(const GramS& g, float au, float bu, float av, float bv) {
    return au * av * g.X2 + (au * bv + bu * av) * g.XY + bu * bv * g.Y2;
}

__device__ __forceinline__ void madd_c(float c, float u2, float v2, float uv,
                                       float au, float bu, float av, float bv,
                                       float& ao, float& bo) {
    float twocuv = 2.0f * c * uv;
    float A = 1.0f + twocuv + c * v2;
    float B = 1.0f - c * u2;
    float rden = rcp_fast(fmaxf(1.0f + twocuv + c * c * u2 * v2, F_EPS));
    ao = (A * au + B * av) * rden;
    bo = (A * bu + B * bv) * rden;
}

__device__ __forceinline__ float pclip(const GramS& g, float maxn_post, float& a, float& b) {
    float n = fmaxf(sqrt_fast(gnorm2(g, a, b)), F_EPS);
    float s = fminf(1.0f, maxn_post * rcp_fast(n));
    a *= s; b *= s;
    return s * n;                       // == min(n, maxn_post)
}

__device__ __forceinline__ float msm_coef(float sc, float rcp_sc, float r,
                                          float n_in, float& n_out) {
    float ne = fmaxf(n_in, F_EPS);
    float z  = fminf(sc * ne, F_ATANH_MAX);
    float w  = tanh_fast(r * atanh_fast(z));
    float m  = w * rcp_fast(sc * ne);
    float aw = fabsf(w);
    float s  = fminf(1.0f, F_BALL * rcp_fast(fmaxf(aw, F_EPS)));   // post_clip
    n_out = s * aw * rcp_sc;
    return m * s;
}

__device__ __forceinline__ float hr_c(float nx, float sc, float rcp_sc,
                                      float maxn_pre, float& n_out) {
    float s1 = fminf(1.0f, maxn_pre * rcp_fast(nx));    // pre_clip (nx >= EPS)
    float n1 = fmaxf(s1 * nx, F_EPS);
    float t  = tanh_fast(sc * n1);                      // >= 0
    float f1 = t * rcp_fast(sc * n1);                   // expmap0 coef
    float s2 = fminf(1.0f, F_BALL * rcp_fast(fmaxf(t, F_EPS)));  // post_clip
    n_out = s2 * t * rcp_sc;
    return s1 * f1 * s2;
}

__device__ __forceinline__ void chain_row(float gX2, float gY2, float gXY,
                                          const ChainP& P, float& fa, float& fb) {
    GramS g; g.X2 = gX2; g.Y2 = gY2; g.XY = gXY;
    const float c = P.c, sc = P.sc, rcp_sc = P.rcp_sc;
    const float maxn_pre = P.maxn_pre, maxn_post = P.maxn_post;

    const float nx = fmaxf(sqrt_fast(gX2), F_EPS);
    const float ny = fmaxf(sqrt_fast(gY2), F_EPS);

    float n_hx, n_hy;
    const float hx = hr_c(nx, sc, rcp_sc, maxn_pre, n_hx);       // hr_x = hx * x
    const float hy = hr_c(ny, sc, rcp_sc, maxn_pre, n_hy);       // hr_y = hy * y

    float n_sx, n_sy;
    const float sxa = hx * msm_coef(sc, rcp_sc, P.s,        n_hx, n_sx);
    const float syb = hy * msm_coef(sc, rcp_sc, 1.0f - P.s, n_hy, n_sy);

    float pa, pb;
    {
        float u2 = n_sx * n_sx, v2 = n_sy * n_sy;
        float uv = sxa * syb * gXY;
        madd_c(c, u2, v2, uv, sxa, 0.0f, 0.0f, syb, pa, pb);
    }
    const float n_p = pclip(g, maxn_post, pa, pb);
    const float np2 = n_p * n_p;

    float xpa, xpb;
    {
        float v2 = n_hx * n_hx;
        float uv = -hx * (pa * gX2 + pb * gXY);
        madd_c(c, np2, v2, uv, -pa, -pb, hx, 0.0f, xpa, xpb);
    }
    const float n_xp = pclip(g, maxn_post, xpa, xpb);

    float ypa, ypb;
    {
        float v2 = n_hy * n_hy;
        float uv = -hy * (pa * gXY + pb * gY2);
        madd_c(c, np2, v2, uv, -pa, -pb, 0.0f, hy, ypa, ypb);
    }
    float n_yp = pclip(g, maxn_post, ypa, ypb);

    float n_ys;
    {
        float m = msm_coef(sc, rcp_sc, P.gamma, n_yp, n_ys);
        ypa *= m; ypb *= m;
    }

    float ha, hb;
    {
        float u2 = n_xp * n_xp, v2 = n_ys * n_ys;
        float uv = gdot(g, xpa, xpb, ypa, ypb);
        madd_c(c, u2, v2, uv, xpa, xpb, ypa, ypb, ha, hb);
    }
    const float n_h = pclip(g, maxn_post, ha, hb);

    float ra, rb;
    {
        float u2 = np2, v2 = n_h * n_h;
        float uv = gdot(g, pa, pb, ha, hb);
        madd_c(c, u2, v2, uv, pa, pb, ha, hb, ra, rb);
    }
    const float n_r = pclip(g, maxn_post, ra, rb);

    const float nrr = fmaxf(n_r, F_EPS);
    const float z   = fminf(sc * nrr, F_ATANH_MAX);
    const float f   = atanh_fast(z) * rcp_fast(sc * nrr);
    fa = f * ra;
    fb = f * rb;
}

// ---- 1 row: 6 dwordx4 loads into named register buffer ----
__device__ __forceinline__ void load_row(const float* __restrict__ x,
                                         const float* __restrict__ y,
                                         int row, int lane,
                                         float4 (&xv)[3], float4 (&yv)[3]) {
    const float4* xr = (const float4*)(x + (size_t)row * 768) + lane;
    const float4* yr = (const float4*)(y + (size_t)row * 768) + lane;
    xv[0] = xr[0];  xv[1] = xr[64];  xv[2] = xr[128];
    yv[0] = yr[0];  yv[1] = yr[64];  yv[2] = yr[128];
}

// gram + reduce + chain (redundant on all 64 lanes) + blend + store, from regs
__device__ __forceinline__ void process_row(float4 (&xv)[3], float4 (&yv)[3],
                                            int row, int lane, const ChainP& P,
                                            float* __restrict__ out) {
    float sxx = 0.0f, syy = 0.0f, sxy = 0.0f;
#pragma unroll
    for (int j = 0; j < 3; ++j) {
        sxx += xv[j].x * xv[j].x + xv[j].y * xv[j].y
             + xv[j].z * xv[j].z + xv[j].w * xv[j].w;
        syy += yv[j].x * yv[j].x + yv[j].y * yv[j].y
             + yv[j].z * yv[j].z + yv[j].w * yv[j].w;
        sxy += xv[j].x * yv[j].x + xv[j].y * yv[j].y
             + xv[j].z * yv[j].z + xv[j].w * yv[j].w;
    }

#pragma unroll
    for (int o = 32; o > 0; o >>= 1) {
        sxx += __shfl_xor(sxx, o, 64);
        syy += __shfl_xor(syy, o, 64);
        sxy += __shfl_xor(sxy, o, 64);
    }

    float fa, fb;
    chain_row(sxx, syy, sxy, P, fa, fb);

    float4* outr = (float4*)(out + (size_t)row * 768) + lane;
#pragma unroll
    for (int j = 0; j < 3; ++j) {
        float4 o;
        o.x = fa * xv[j].x + fb * yv[j].x;
        o.y = fa * xv[j].y + fb * yv[j].y;
        o.z = fa * xv[j].z + fb * yv[j].z;
        o.w = fa * xv[j].w + fb * yv[j].w;
        outr[64 * j] = o;
    }
}

// Persistent grid-stride, 1 row/iteration, 2-deep register pipeline:
// next row's 6 loads are issued BEFORE the current row's reduce+chain, so
// every wave keeps ~6KB outstanding through the serial section. 1-row
// buffers (48 VGPR total) leave the allocator slack R5's 2-row version
// (116 VGPR) lacked, so residency stays high AND bursts stay unbroken.
__global__ __launch_bounds__(256) void hra_fused(
    const float* __restrict__ x, const float* __restrict__ y,
    const float* __restrict__ p_curv, const float* __restrict__ p_graw,
    const float* __restrict__ p_gscale, const float* __restrict__ p_scent,
    float* __restrict__ out, int rows)
{
    const int lane = threadIdx.x & 63;
    const int w    = (blockIdx.x << 2) | (threadIdx.x >> 6);
    const int nw   = gridDim.x << 2;
    if (w >= rows) return;

    // wave-uniform params, derived once
    ChainP P;
    P.c         = softplus_fast(p_curv[0]);
    P.sc        = sqrt_fast(P.c);
    P.rcp_sc    = rcp_fast(P.sc);
    P.maxn_pre  = F_TANH_ARG_MAX * P.rcp_sc;
    P.maxn_post = F_BALL * P.rcp_sc;
    P.s         = rcp_fast(1.0f + exp_fast(-p_scent[0]));      // sigmoid
    P.gamma     = (1.0f + softplus_fast(p_gscale[0])) * tanh_fast(p_graw[0]);

    float4 xA[3], yA[3], xB[3], yB[3];

    int row = w;
    load_row(x, y, row, lane, xA, yA);
    while (true) {
        const int rowB = row + nw;
        if (rowB < rows) {
            load_row(x, y, rowB, lane, xB, yB);          // prefetch B
            process_row(xA, yA, row, lane, P, out);      // compute+store A
            const int rowA2 = rowB + nw;
            if (rowA2 < rows) {
                load_row(x, y, rowA2, lane, xA, yA);     // prefetch A
                process_row(xB, yB, rowB, lane, P, out); // compute+store B
                row = rowA2;
            } else {
                process_row(xB, yB, rowB, lane, P, out);
                return;
            }
        } else {
            process_row(xA, yA, row, lane, P, out);
            return;
        }
    }
}

extern "C" void kernel_launch(void* const* d_in, const int* in_sizes, int n_in,
                              void* d_out, int out_size, void* d_ws, size_t ws_size,
                              hipStream_t stream) {
    const float* x = (const float*)d_in[0];
    const float* y = (const float*)d_in[1];
    const float* curv = (const float*)d_in[2];
    const float* graw = (const float*)d_in[3];
    const float* gscale = (const float*)d_in[4];
    const float* scent = (const float*)d_in[5];
    float* out = (float*)d_out;

    const int rows = in_sizes[0] / 768;          // 64*577 = 36928
    // persistent grid: 8 blocks/CU, each wave grid-strides ~4.5 rows
    int blocks = (rows + 3) / 4;
    if (blocks > 2048) blocks = 2048;

    hipLaunchKernelGGL(hra_fused, dim3(blocks), dim3(256), 0, stream,
                       x, y, curv, graw, gscale, scent, out, rows);
}